// Round 5
// baseline (167.599 us; speedup 1.0000x reference)
//
#include <hip/hip_runtime.h>
#include <math.h>

#define HIDDEN 64
#define SEQ 128
#define BATCH 64
#define NPTS (BATCH * SEQ)   // 8192
#define TMAXV 20.0f
#define L2E 1.4426950408889634f
#define LN2 0.6931471805599453f

typedef float v2f __attribute__((ext_vector_type(2)));

__device__ __forceinline__ float fexp2(float x) { return __builtin_amdgcn_exp2f(x); }
__device__ __forceinline__ float flog2(float x) { return __builtin_amdgcn_logf(x); }
__device__ __forceinline__ float frcp(float x)  { return __builtin_amdgcn_rcpf(x); }
__device__ __forceinline__ float fsigmoid(float x) { return frcp(1.0f + fexp2(-x * L2E)); }
__device__ __forceinline__ float ftanh(float x)    { return 1.0f - 2.0f * frcp(1.0f + fexp2(2.0f * x * L2E)); }

// Raw barrier: orders LDS only (lgkmcnt), does NOT drain vmcnt.
__device__ __forceinline__ void barrier_lds_only() {
    asm volatile("s_waitcnt lgkmcnt(0)" ::: "memory");
    __builtin_amdgcn_s_barrier();
}

// ---- DPP wave64 sum: VALU-pipe cross-lane (no LDS round trips). Result uniform.
template <int CTRL>
__device__ __forceinline__ float dpp_mov(float x) {
    int r = __builtin_amdgcn_update_dpp(0, __float_as_int(x), CTRL, 0xf, 0xf, false);
    return __int_as_float(r);
}
__device__ __forceinline__ float wave_sum_dpp(float x) {
    x += dpp_mov<0x111>(x);   // row_shr:1
    x += dpp_mov<0x112>(x);   // row_shr:2
    x += dpp_mov<0x114>(x);   // row_shr:4
    x += dpp_mov<0x118>(x);   // row_shr:8  -> lane 16r+15 = row sum
    x += dpp_mov<0x142>(x);   // row_bcast:15
    x += dpp_mov<0x143>(x);   // row_bcast:31 -> lane 63 = total
    return __int_as_float(__builtin_amdgcn_readlane(__float_as_int(x), 63));
}

__device__ __forceinline__ float wave_sum_shfl(float v) {
    v += __shfl_xor(v, 1);  v += __shfl_xor(v, 2);  v += __shfl_xor(v, 4);
    v += __shfl_xor(v, 8);  v += __shfl_xor(v, 16); v += __shfl_xor(v, 32);
    return v;
}

// Blocks [0,64): LSTM rollout, one batch per block, 256 threads (thread j = gate-row j).
// KEY CHANGE vs the 68us version: W_hh staged in LDS once (chunked [16][256][4]
// layout -> each wave's ds_read_b128 is a contiguous 1024B = conflict-free,
// 256 B/clock). Previously VGPR=52 proved weights were re-streamed from L2
// every step (64 KB/step/CU ~ 1170 cy/step, the measured floor); the compiler
// refused register residency twice. LDS read: 16 b128/thread/step, weights
// written and read by the SAME thread -> no extra barrier needed.
// Blocks [64,192): expert-expert MMD term (input-only) on the idle CUs.
__global__ __launch_bounds__(256) void gen_and_ee(
    const float* __restrict__ upool,   // [B,S]
    const float* __restrict__ texp,    // [B,S]
    const float* __restrict__ Wih,     // [256]
    const float* __restrict__ Whh,     // [256,64]
    const float* __restrict__ bih,     // [256]
    const float* __restrict__ bhh,     // [256]
    const float* __restrict__ Vw,      // [64]
    const float* __restrict__ Vb,      // [1]
    float* __restrict__ tl,            // [NPTS] workspace
    float* __restrict__ out)           // [1] loss accumulator
{
    __shared__ __align__(16) float w_s[16][256][4];   // 64 KB: chunk k, row tid, 4 cols
    __shared__ float lu_s[SEQ];
    __shared__ float act_s[2][256];                 // double-buffered gate activations
    __shared__ __align__(16) float hx_s[4][64];     // per-wave private hx replicas
    __shared__ float2 qbuf[2048];

    const int bid = blockIdx.x;
    const int tid = threadIdx.x;

    if (bid < BATCH) {
        const int h  = tid & 63;
        const int wv = tid >> 6;

        // Stage W_hh row `tid` into LDS chunked layout (one-time, ~64KB from L2).
        {
            const float4* wrow = (const float4*)(Whh + tid * 64);
            float4* wdst = (float4*)w_s;          // chunk stride = 256 float4
            #pragma unroll
            for (int k = 0; k < 16; ++k) wdst[k * 256 + tid] = wrow[k];
        }
        const float bias = bih[tid] + bhh[tid];
        const float wih  = Wih[tid];
        const float vw   = Vw[h];      // all waves: redundant sigma reduction
        const float vb   = Vb[0];

        if (tid < SEQ) lu_s[tid] = -flog2(upool[bid * SEQ + tid]) * LN2;
        hx_s[wv][h] = 0.0f;            // every wave zeroes its own replica
        float cx = 0.0f;
        barrier_lds_only();

        // step 0: hx = 0 -> sigma = elu(Vb)+1 (uniform)
        float sg0 = (vb > 0.0f) ? (vb + 1.0f) : fexp2(vb * L2E);
        float cum = lu_s[0] * frcp(sg0);
        float keep = (tid == 0) ? cum : 0.0f;   // thread t keeps cum of step t

        const float4* wl = ((const float4*)w_s) + tid;   // per-thread weight base

        #pragma unroll 1
        for (int s = 0; s < SEQ - 1; ++s) {
            // gate-row dot hx, from this wave's private replica (broadcast b128 reads)
            const float4* h4 = (const float4*)hx_s[wv];
            v2f a0 = {0.f, 0.f}, a1 = {0.f, 0.f}, a2 = {0.f, 0.f}, a3 = {0.f, 0.f};
            #pragma unroll
            for (int k = 0; k < 16; k += 2) {
                float4 wA = wl[k * 256];          // cols 4k..4k+3   (ds_read_b128)
                float4 wB = wl[(k + 1) * 256];    // cols 4k+4..4k+7
                float4 va = h4[k];
                float4 vbq = h4[k + 1];
                // identical FMA pairing/order as the w2[] version (bit-exact)
                a0 = a0 + (v2f){wA.x, wA.y} * (v2f){va.x, va.y};
                a1 = a1 + (v2f){wA.z, wA.w} * (v2f){va.z, va.w};
                a2 = a2 + (v2f){wB.x, wB.y} * (v2f){vbq.x, vbq.y};
                a3 = a3 + (v2f){wB.z, wB.w} * (v2f){vbq.z, vbq.w};
            }
            v2f aa = (a0 + a1) + (a2 + a3);
            float g = (aa.x + aa.y) + bias + cum * wih;
            float a = (wv == 2) ? ftanh(g) : fsigmoid(g);
            act_s[s & 1][tid] = a;
            barrier_lds_only();        // the ONLY barrier per step; no vmcnt drain

            // redundant cell update in every wave (bit-identical across waves)
            float ig = act_s[s & 1][h];
            float fg = act_s[s & 1][64 + h];
            float gg = act_s[s & 1][128 + h];
            float og = act_s[s & 1][192 + h];
            cx = fg * cx + ig * gg;
            float hx = og * ftanh(cx);
            hx_s[wv][h] = hx;          // own replica; in-wave lgkmcnt ordering only

            float tot = wave_sum_dpp(hx * vw);
            float xx  = tot + vb;
            float sg  = (xx > 0.0f) ? (xx + 1.0f) : fexp2(xx * L2E);
            cum += lu_s[s + 1] * frcp(sg);

            keep = (tid == s + 1) ? cum : keep;   // threads 128..255 never match
        }
        if (tid < SEQ) tl[bid * SEQ + tid] = keep;
    } else {
        // ---------------- expert-expert MMD term ----------------
        const int eb = bid - BATCH;      // 0..127
        const int pc = eb & 31;          // p-chunk (256 points)
        const int qs = eb >> 5;          // q-split (2048 points)

        const int p = pc * 256 + tid;
        const float tp = texp[p];
        const float mp = (tp < TMAXV && tp > 0.0f) ? 1.0f : 0.0f;

        const int q0 = qs * 2048;
        for (int i = tid; i < 2048; i += 256) {
            float tq = texp[q0 + i];
            float mq = (tq < TMAXV && tq > 0.0f) ? 1.0f : 0.0f;
            qbuf[i] = make_float2(tq, mq);
        }
        __syncthreads();

        float acc = 0.0f;
        #pragma unroll 4
        for (int i = 0; i < 2048; ++i) {
            float2 qq = qbuf[i];
            float d = tp - qq.x;
            acc = fmaf(qq.y, fexp2(d * d * (-L2E)), acc);
        }
        acc *= mp;
        acc = wave_sum_shfl(acc);
        if ((tid & 63) == 0) atomicAdd(out, acc);
    }
}

// ll + le terms. Grid (32, 16): 32 p-chunks of 256 x 16 q-splits of 512.
__global__ __launch_bounds__(256) void ll_le(
    const float* __restrict__ texp,
    const float* __restrict__ tl,
    float* __restrict__ out)
{
    __shared__ __align__(16) float4 qbuf[512];
    __shared__ float red[4];

    const int pc = blockIdx.x;
    const int qs = blockIdx.y;
    const int tid = threadIdx.x;

    const int p = pc * 256 + tid;
    const float tlp = tl[p];
    const float mlp = (tlp < TMAXV && tlp > 0.0f) ? 1.0f : 0.0f;

    const int q0 = qs * 512;
    for (int i = tid; i < 512; i += 256) {
        float tq = tl[q0 + i];
        float mq = (tq < TMAXV && tq > 0.0f) ? 1.0f : 0.0f;
        float te = texp[q0 + i];
        float me = (te < TMAXV && te > 0.0f) ? 1.0f : 0.0f;
        qbuf[i] = make_float4(tq, mq, te, me);
    }
    __syncthreads();

    float val = 0.0f;
    // learner times are cumsum of Exp(1) increments: most p-points exceed T_MAX;
    // fully-masked waves skip the whole q-loop (wave-uniform branch).
    if (__ballot(mlp != 0.0f) != 0ULL) {
        float a_ll = 0.0f, a_le = 0.0f;
        #pragma unroll 4
        for (int i = 0; i < 512; ++i) {
            float4 q = qbuf[i];
            float d1 = tlp - q.x;
            a_ll = fmaf(q.y, fexp2(d1 * d1 * (-L2E)), a_ll);
            float d2 = tlp - q.z;
            a_le = fmaf(q.w, fexp2(d2 * d2 * (-L2E)), a_le);
        }
        val = mlp * (a_ll - 2.0f * a_le);
    }

    val = wave_sum_shfl(val);
    if ((tid & 63) == 0) red[tid >> 6] = val;
    __syncthreads();
    if (tid == 0) atomicAdd(out, red[0] + red[1] + red[2] + red[3]);
}

extern "C" void kernel_launch(void* const* d_in, const int* in_sizes, int n_in,
                              void* d_out, int out_size, void* d_ws, size_t ws_size,
                              hipStream_t stream) {
    const float* upool = (const float*)d_in[0];
    const float* texp  = (const float*)d_in[1];
    const float* Wih   = (const float*)d_in[2];
    const float* Whh   = (const float*)d_in[3];
    const float* bih   = (const float*)d_in[4];
    const float* bhh   = (const float*)d_in[5];
    const float* Vw    = (const float*)d_in[6];
    const float* Vb    = (const float*)d_in[7];
    float* out = (float*)d_out;
    float* tl  = (float*)d_ws;   // 8192 floats = 32 KB

    hipMemsetAsync(out, 0, sizeof(float), stream);
    hipLaunchKernelGGL(gen_and_ee, dim3(BATCH + 128), dim3(256), 0, stream,
                       upool, texp, Wih, Whh, bih, bhh, Vw, Vb, tl, out);
    hipLaunchKernelGGL(ll_le, dim3(32, 16), dim3(256), 0, stream, texp, tl, out);
}

// Round 6
// 162.391 us; speedup vs baseline: 1.0321x; 1.0321x over previous
//
#include <hip/hip_runtime.h>
#include <math.h>

#define HIDDEN 64
#define SEQ 128
#define BATCH 64
#define NPTS (BATCH * SEQ)   // 8192
#define TMAXV 20.0f
#define L2E 1.4426950408889634f
#define LN2 0.6931471805599453f

typedef float v2f __attribute__((ext_vector_type(2)));

__device__ __forceinline__ float fexp2(float x) { return __builtin_amdgcn_exp2f(x); }
__device__ __forceinline__ float flog2(float x) { return __builtin_amdgcn_logf(x); }
__device__ __forceinline__ float frcp(float x)  { return __builtin_amdgcn_rcpf(x); }
__device__ __forceinline__ float fsigmoid(float x) { return frcp(1.0f + fexp2(-x * L2E)); }
__device__ __forceinline__ float ftanh(float x)    { return 1.0f - 2.0f * frcp(1.0f + fexp2(2.0f * x * L2E)); }

// Raw barrier: orders LDS only (lgkmcnt), does NOT drain vmcnt.
__device__ __forceinline__ void barrier_lds_only() {
    asm volatile("s_waitcnt lgkmcnt(0)" ::: "memory");
    __builtin_amdgcn_s_barrier();
}

// ---- DPP wave64 sum: VALU-pipe cross-lane (no LDS round trips). Result uniform.
template <int CTRL>
__device__ __forceinline__ float dpp_mov(float x) {
    int r = __builtin_amdgcn_update_dpp(0, __float_as_int(x), CTRL, 0xf, 0xf, false);
    return __int_as_float(r);
}
__device__ __forceinline__ float wave_sum_dpp(float x) {
    x += dpp_mov<0x111>(x);   // row_shr:1
    x += dpp_mov<0x112>(x);   // row_shr:2
    x += dpp_mov<0x114>(x);   // row_shr:4
    x += dpp_mov<0x118>(x);   // row_shr:8  -> lane 16r+15 = row sum
    x += dpp_mov<0x142>(x);   // row_bcast:15
    x += dpp_mov<0x143>(x);   // row_bcast:31 -> lane 63 = total
    return __int_as_float(__builtin_amdgcn_readlane(__float_as_int(x), 63));
}

__device__ __forceinline__ float wave_sum_shfl(float v) {
    v += __shfl_xor(v, 1);  v += __shfl_xor(v, 2);  v += __shfl_xor(v, 4);
    v += __shfl_xor(v, 8);  v += __shfl_xor(v, 16); v += __shfl_xor(v, 32);
    return v;
}

// Blocks [0,64): LSTM rollout, one batch per block, 256 threads (thread j = gate-row j).
// SPLIT WEIGHT DELIVERY: per-CU weight re-read (64 KB/step) is the measured wall.
//   - one pipe alone: VMEM/L1 ~1000 cy/step (68us, r3) or LDS ~1500 cy/step (81us, r5).
//   - chunks 0-7 (32 KB) from LDS (conflict-free chunked layout, r5-proven);
//   - chunks 8-15 (32 KB) from global inside the loop (r3-proven); this half
//     now FITS the 32 KB L1 -> L1-hits, and runs on the VMEM pipe CONCURRENT
//     with the LDS reads. Same values, same FMA order -> bit-identical.
// Blocks [64,192): expert-expert MMD term (input-only) on the idle CUs.
__global__ __launch_bounds__(256) void gen_and_ee(
    const float* __restrict__ upool,   // [B,S]
    const float* __restrict__ texp,    // [B,S]
    const float* __restrict__ Wih,     // [256]
    const float* __restrict__ Whh,     // [256,64]
    const float* __restrict__ bih,     // [256]
    const float* __restrict__ bhh,     // [256]
    const float* __restrict__ Vw,      // [64]
    const float* __restrict__ Vb,      // [1]
    float* __restrict__ tl,            // [NPTS] workspace
    float* __restrict__ out)           // [1] loss accumulator
{
    __shared__ __align__(16) float w_s[8][256][4];  // 32 KB: chunks 0-7, row tid, 4 cols
    __shared__ float lu_s[SEQ];
    __shared__ float act_s[2][256];                 // double-buffered gate activations
    __shared__ __align__(16) float hx_s[4][64];     // per-wave private hx replicas
    __shared__ float2 qbuf[2048];

    const int bid = blockIdx.x;
    const int tid = threadIdx.x;

    if (bid < BATCH) {
        const int h  = tid & 63;
        const int wv = tid >> 6;

        // Stage chunks 0-7 of W_hh row `tid` into LDS (one-time).
        {
            const float4* wrow = (const float4*)(Whh + tid * 64);
            float4* wdst = (float4*)w_s;          // chunk stride = 256 float4
            #pragma unroll
            for (int k = 0; k < 8; ++k) wdst[k * 256 + tid] = wrow[k];
        }
        const float bias = bih[tid] + bhh[tid];
        const float wih  = Wih[tid];
        const float vw   = Vw[h];      // all waves: redundant sigma reduction
        const float vb   = Vb[0];

        if (tid < SEQ) lu_s[tid] = -flog2(upool[bid * SEQ + tid]) * LN2;
        hx_s[wv][h] = 0.0f;            // every wave zeroes its own replica
        float cx = 0.0f;
        barrier_lds_only();

        // step 0: hx = 0 -> sigma = elu(Vb)+1 (uniform)
        float sg0 = (vb > 0.0f) ? (vb + 1.0f) : fexp2(vb * L2E);
        float cum = lu_s[0] * frcp(sg0);
        float keep = (tid == 0) ? cum : 0.0f;   // thread t keeps cum of step t

        const float4* wl = ((const float4*)w_s) + tid;            // LDS half base
        const float4* wg = ((const float4*)(Whh + tid * 64)) + 8; // global half base

        #pragma unroll 1
        for (int s = 0; s < SEQ - 1; ++s) {
            // Issue the VMEM half first so L1 hits overlap the LDS half + FMAs.
            float4 gw[8];
            #pragma unroll
            for (int k = 0; k < 8; ++k) gw[k] = wg[k];

            // gate-row dot hx, from this wave's private replica (broadcast b128 reads)
            const float4* h4 = (const float4*)hx_s[wv];
            v2f a0 = {0.f, 0.f}, a1 = {0.f, 0.f}, a2 = {0.f, 0.f}, a3 = {0.f, 0.f};
            #pragma unroll
            for (int k = 0; k < 16; k += 2) {
                float4 wA = (k < 8) ? wl[k * 256]       : gw[k - 8];
                float4 wB = (k < 8) ? wl[(k + 1) * 256] : gw[k - 7];
                float4 va = h4[k];
                float4 vbq = h4[k + 1];
                // identical FMA pairing/order as before (bit-exact)
                a0 = a0 + (v2f){wA.x, wA.y} * (v2f){va.x, va.y};
                a1 = a1 + (v2f){wA.z, wA.w} * (v2f){va.z, va.w};
                a2 = a2 + (v2f){wB.x, wB.y} * (v2f){vbq.x, vbq.y};
                a3 = a3 + (v2f){wB.z, wB.w} * (v2f){vbq.z, vbq.w};
            }
            v2f aa = (a0 + a1) + (a2 + a3);
            float g = (aa.x + aa.y) + bias + cum * wih;
            float a = (wv == 2) ? ftanh(g) : fsigmoid(g);
            act_s[s & 1][tid] = a;
            barrier_lds_only();        // the ONLY barrier per step; no vmcnt drain

            // redundant cell update in every wave (bit-identical across waves)
            float ig = act_s[s & 1][h];
            float fg = act_s[s & 1][64 + h];
            float gg = act_s[s & 1][128 + h];
            float og = act_s[s & 1][192 + h];
            cx = fg * cx + ig * gg;
            float hx = og * ftanh(cx);
            hx_s[wv][h] = hx;          // own replica; in-wave lgkmcnt ordering only

            float tot = wave_sum_dpp(hx * vw);
            float xx  = tot + vb;
            float sg  = (xx > 0.0f) ? (xx + 1.0f) : fexp2(xx * L2E);
            cum += lu_s[s + 1] * frcp(sg);

            keep = (tid == s + 1) ? cum : keep;   // threads 128..255 never match
        }
        if (tid < SEQ) tl[bid * SEQ + tid] = keep;
    } else {
        // ---------------- expert-expert MMD term ----------------
        const int eb = bid - BATCH;      // 0..127
        const int pc = eb & 31;          // p-chunk (256 points)
        const int qs = eb >> 5;          // q-split (2048 points)

        const int p = pc * 256 + tid;
        const float tp = texp[p];
        const float mp = (tp < TMAXV && tp > 0.0f) ? 1.0f : 0.0f;

        const int q0 = qs * 2048;
        for (int i = tid; i < 2048; i += 256) {
            float tq = texp[q0 + i];
            float mq = (tq < TMAXV && tq > 0.0f) ? 1.0f : 0.0f;
            qbuf[i] = make_float2(tq, mq);
        }
        __syncthreads();

        float acc = 0.0f;
        #pragma unroll 4
        for (int i = 0; i < 2048; ++i) {
            float2 qq = qbuf[i];
            float d = tp - qq.x;
            acc = fmaf(qq.y, fexp2(d * d * (-L2E)), acc);
        }
        acc *= mp;
        acc = wave_sum_shfl(acc);
        if ((tid & 63) == 0) atomicAdd(out, acc);
    }
}

// ll + le terms. Grid (32, 16): 32 p-chunks of 256 x 16 q-splits of 512.
__global__ __launch_bounds__(256) void ll_le(
    const float* __restrict__ texp,
    const float* __restrict__ tl,
    float* __restrict__ out)
{
    __shared__ __align__(16) float4 qbuf[512];
    __shared__ float red[4];

    const int pc = blockIdx.x;
    const int qs = blockIdx.y;
    const int tid = threadIdx.x;

    const int p = pc * 256 + tid;
    const float tlp = tl[p];
    const float mlp = (tlp < TMAXV && tlp > 0.0f) ? 1.0f : 0.0f;

    const int q0 = qs * 512;
    for (int i = tid; i < 512; i += 256) {
        float tq = tl[q0 + i];
        float mq = (tq < TMAXV && tq > 0.0f) ? 1.0f : 0.0f;
        float te = texp[q0 + i];
        float me = (te < TMAXV && te > 0.0f) ? 1.0f : 0.0f;
        qbuf[i] = make_float4(tq, mq, te, me);
    }
    __syncthreads();

    float val = 0.0f;
    // learner times are cumsum of Exp(1) increments: most p-points exceed T_MAX;
    // fully-masked waves skip the whole q-loop (wave-uniform branch).
    if (__ballot(mlp != 0.0f) != 0ULL) {
        float a_ll = 0.0f, a_le = 0.0f;
        #pragma unroll 4
        for (int i = 0; i < 512; ++i) {
            float4 q = qbuf[i];
            float d1 = tlp - q.x;
            a_ll = fmaf(q.y, fexp2(d1 * d1 * (-L2E)), a_ll);
            float d2 = tlp - q.z;
            a_le = fmaf(q.w, fexp2(d2 * d2 * (-L2E)), a_le);
        }
        val = mlp * (a_ll - 2.0f * a_le);
    }

    val = wave_sum_shfl(val);
    if ((tid & 63) == 0) red[tid >> 6] = val;
    __syncthreads();
    if (tid == 0) atomicAdd(out, red[0] + red[1] + red[2] + red[3]);
}

extern "C" void kernel_launch(void* const* d_in, const int* in_sizes, int n_in,
                              void* d_out, int out_size, void* d_ws, size_t ws_size,
                              hipStream_t stream) {
    const float* upool = (const float*)d_in[0];
    const float* texp  = (const float*)d_in[1];
    const float* Wih   = (const float*)d_in[2];
    const float* Whh   = (const float*)d_in[3];
    const float* bih   = (const float*)d_in[4];
    const float* bhh   = (const float*)d_in[5];
    const float* Vw    = (const float*)d_in[6];
    const float* Vb    = (const float*)d_in[7];
    float* out = (float*)d_out;
    float* tl  = (float*)d_ws;   // 8192 floats = 32 KB

    hipMemsetAsync(out, 0, sizeof(float), stream);
    hipLaunchKernelGGL(gen_and_ee, dim3(BATCH + 128), dim3(256), 0, stream,
                       upool, texp, Wih, Whh, bih, bhh, Vw, Vb, tl, out);
    hipLaunchKernelGGL(ll_le, dim3(32, 16), dim3(256), 0, stream, texp, tl, out);
}

// Round 7
// 158.005 us; speedup vs baseline: 1.0607x; 1.0278x over previous
//
#include <hip/hip_runtime.h>
#include <math.h>

#define HIDDEN 64
#define SEQ 128
#define BATCH 64
#define NPTS (BATCH * SEQ)   // 8192
#define TMAXV 20.0f
#define L2E 1.4426950408889634f
#define LN2 0.6931471805599453f

typedef float v2f __attribute__((ext_vector_type(2)));

__device__ __forceinline__ float fexp2(float x) { return __builtin_amdgcn_exp2f(x); }
__device__ __forceinline__ float flog2(float x) { return __builtin_amdgcn_logf(x); }
__device__ __forceinline__ float frcp(float x)  { return __builtin_amdgcn_rcpf(x); }
__device__ __forceinline__ float fsigmoid(float x) { return frcp(1.0f + fexp2(-x * L2E)); }
__device__ __forceinline__ float ftanh(float x)    { return 1.0f - 2.0f * frcp(1.0f + fexp2(2.0f * x * L2E)); }

// Raw barrier: orders LDS only (lgkmcnt), does NOT drain vmcnt.
__device__ __forceinline__ void barrier_lds_only() {
    asm volatile("s_waitcnt lgkmcnt(0)" ::: "memory");
    __builtin_amdgcn_s_barrier();
}

// ---- DPP wave64 sum: VALU-pipe cross-lane (no LDS round trips). Result uniform.
template <int CTRL>
__device__ __forceinline__ float dpp_mov(float x) {
    int r = __builtin_amdgcn_update_dpp(0, __float_as_int(x), CTRL, 0xf, 0xf, false);
    return __int_as_float(r);
}
__device__ __forceinline__ float wave_sum_dpp(float x) {
    x += dpp_mov<0x111>(x);   // row_shr:1
    x += dpp_mov<0x112>(x);   // row_shr:2
    x += dpp_mov<0x114>(x);   // row_shr:4
    x += dpp_mov<0x118>(x);   // row_shr:8  -> lane 16r+15 = row sum
    x += dpp_mov<0x142>(x);   // row_bcast:15
    x += dpp_mov<0x143>(x);   // row_bcast:31 -> lane 63 = total
    return __int_as_float(__builtin_amdgcn_readlane(__float_as_int(x), 63));
}

__device__ __forceinline__ float wave_sum_shfl(float v) {
    v += __shfl_xor(v, 1);  v += __shfl_xor(v, 2);  v += __shfl_xor(v, 4);
    v += __shfl_xor(v, 8);  v += __shfl_xor(v, 16); v += __shfl_xor(v, 32);
    return v;
}

// Blocks [0,64): LSTM rollout, one batch per block, 256 threads (thread j = gate-row j).
// KEY CHANGE vs r3 (68us): W_hh row loaded ONCE via a single asm volatile block
// (16x global_load_dwordx4 + s_waitcnt vmcnt(0), early-clobber "=&v" float4
// outputs). Volatile-asm results are NOT rematerializable -> the compiler must
// keep the 64 weight VGPRs live across the step loop (budget 512 via
// __launch_bounds__(256,1); 1 block/CU so no occupancy pressure). This removes
// the 64 KB/step/CU weight re-stream that r3/r5/r6 proved is the wall on every
// memory pipe (VMEM ~1024 cy, LDS ~1500 cy, split ~1373 cy per step).
// Blocks [64,192): expert-expert MMD term (input-only) on the idle CUs.
__global__ __launch_bounds__(256, 1) void gen_and_ee(
    const float* __restrict__ upool,   // [B,S]
    const float* __restrict__ texp,    // [B,S]
    const float* __restrict__ Wih,     // [256]
    const float* __restrict__ Whh,     // [256,64]
    const float* __restrict__ bih,     // [256]
    const float* __restrict__ bhh,     // [256]
    const float* __restrict__ Vw,      // [64]
    const float* __restrict__ Vb,      // [1]
    float* __restrict__ tl,            // [NPTS] workspace
    float* __restrict__ out)           // [1] loss accumulator
{
    __shared__ float lu_s[SEQ];
    __shared__ float act_s[2][256];                 // double-buffered gate activations
    __shared__ __align__(16) float hx_s[4][64];     // per-wave private hx replicas
    __shared__ float2 qbuf[2048];

    const int bid = blockIdx.x;
    const int tid = threadIdx.x;

    if (bid < BATCH) {
        const int h  = tid & 63;
        const int wv = tid >> 6;

        // W_hh row `tid` -> registers, via non-rematerializable asm loads.
        float4 w0, w1, w2_, w3, w4, w5, w6, w7, w8, w9, w10, w11, w12, w13, w14, w15;
        {
            const float4* wrow = (const float4*)(Whh + tid * 64);
            asm volatile(
                "global_load_dwordx4 %0, %16, off\n\t"
                "global_load_dwordx4 %1, %16, off offset:16\n\t"
                "global_load_dwordx4 %2, %16, off offset:32\n\t"
                "global_load_dwordx4 %3, %16, off offset:48\n\t"
                "global_load_dwordx4 %4, %16, off offset:64\n\t"
                "global_load_dwordx4 %5, %16, off offset:80\n\t"
                "global_load_dwordx4 %6, %16, off offset:96\n\t"
                "global_load_dwordx4 %7, %16, off offset:112\n\t"
                "global_load_dwordx4 %8, %16, off offset:128\n\t"
                "global_load_dwordx4 %9, %16, off offset:144\n\t"
                "global_load_dwordx4 %10, %16, off offset:160\n\t"
                "global_load_dwordx4 %11, %16, off offset:176\n\t"
                "global_load_dwordx4 %12, %16, off offset:192\n\t"
                "global_load_dwordx4 %13, %16, off offset:208\n\t"
                "global_load_dwordx4 %14, %16, off offset:224\n\t"
                "global_load_dwordx4 %15, %16, off offset:240\n\t"
                "s_waitcnt vmcnt(0)"
                : "=&v"(w0), "=&v"(w1), "=&v"(w2_), "=&v"(w3),
                  "=&v"(w4), "=&v"(w5), "=&v"(w6),  "=&v"(w7),
                  "=&v"(w8), "=&v"(w9), "=&v"(w10), "=&v"(w11),
                  "=&v"(w12), "=&v"(w13), "=&v"(w14), "=&v"(w15)
                : "v"(wrow)
                : "memory");
        }
        const float bias = bih[tid] + bhh[tid];
        const float wih  = Wih[tid];
        const float vw   = Vw[h];      // all waves: redundant sigma reduction
        const float vb   = Vb[0];

        if (tid < SEQ) lu_s[tid] = -flog2(upool[bid * SEQ + tid]) * LN2;
        hx_s[wv][h] = 0.0f;            // every wave zeroes its own replica
        float cx = 0.0f;
        barrier_lds_only();

        // step 0: hx = 0 -> sigma = elu(Vb)+1 (uniform)
        float sg0 = (vb > 0.0f) ? (vb + 1.0f) : fexp2(vb * L2E);
        float cum = lu_s[0] * frcp(sg0);
        float keep = (tid == 0) ? cum : 0.0f;   // thread t keeps cum of step t

        #pragma unroll 1
        for (int s = 0; s < SEQ - 1; ++s) {
            // gate-row dot hx, from this wave's private replica (broadcast b128 reads)
            const float4* h4 = (const float4*)hx_s[wv];
            v2f a0 = {0.f, 0.f}, a1 = {0.f, 0.f}, a2 = {0.f, 0.f}, a3 = {0.f, 0.f};
            // identical FMA pairing/order as r0/r3 (bit-exact):
            //   pair (k,k+1): a0+=w[k].xy*h[k].xy; a1+=w[k].zw*h[k].zw;
            //                 a2+=w[k+1].xy*h[k+1].xy; a3+=w[k+1].zw*h[k+1].zw;
#define GATE_PAIR(K, WA, WB)                                            \
            {                                                           \
                float4 va = h4[K];                                      \
                float4 vbq = h4[(K) + 1];                               \
                a0 = a0 + (v2f){WA.x, WA.y} * (v2f){va.x, va.y};        \
                a1 = a1 + (v2f){WA.z, WA.w} * (v2f){va.z, va.w};        \
                a2 = a2 + (v2f){WB.x, WB.y} * (v2f){vbq.x, vbq.y};      \
                a3 = a3 + (v2f){WB.z, WB.w} * (v2f){vbq.z, vbq.w};      \
            }
            GATE_PAIR(0,  w0,  w1)
            GATE_PAIR(2,  w2_, w3)
            GATE_PAIR(4,  w4,  w5)
            GATE_PAIR(6,  w6,  w7)
            GATE_PAIR(8,  w8,  w9)
            GATE_PAIR(10, w10, w11)
            GATE_PAIR(12, w12, w13)
            GATE_PAIR(14, w14, w15)
#undef GATE_PAIR
            v2f aa = (a0 + a1) + (a2 + a3);
            float g = (aa.x + aa.y) + bias + cum * wih;
            float a = (wv == 2) ? ftanh(g) : fsigmoid(g);
            act_s[s & 1][tid] = a;
            barrier_lds_only();        // the ONLY barrier per step; no vmcnt drain

            // redundant cell update in every wave (bit-identical across waves)
            float ig = act_s[s & 1][h];
            float fg = act_s[s & 1][64 + h];
            float gg = act_s[s & 1][128 + h];
            float og = act_s[s & 1][192 + h];
            cx = fg * cx + ig * gg;
            float hx = og * ftanh(cx);
            hx_s[wv][h] = hx;          // own replica; in-wave lgkmcnt ordering only

            float tot = wave_sum_dpp(hx * vw);
            float xx  = tot + vb;
            float sg  = (xx > 0.0f) ? (xx + 1.0f) : fexp2(xx * L2E);
            cum += lu_s[s + 1] * frcp(sg);

            keep = (tid == s + 1) ? cum : keep;   // threads 128..255 never match
        }
        if (tid < SEQ) tl[bid * SEQ + tid] = keep;
    } else {
        // ---------------- expert-expert MMD term ----------------
        const int eb = bid - BATCH;      // 0..127
        const int pc = eb & 31;          // p-chunk (256 points)
        const int qs = eb >> 5;          // q-split (2048 points)

        const int p = pc * 256 + tid;
        const float tp = texp[p];
        const float mp = (tp < TMAXV && tp > 0.0f) ? 1.0f : 0.0f;

        const int q0 = qs * 2048;
        for (int i = tid; i < 2048; i += 256) {
            float tq = texp[q0 + i];
            float mq = (tq < TMAXV && tq > 0.0f) ? 1.0f : 0.0f;
            qbuf[i] = make_float2(tq, mq);
        }
        __syncthreads();

        float acc = 0.0f;
        #pragma unroll 4
        for (int i = 0; i < 2048; ++i) {
            float2 qq = qbuf[i];
            float d = tp - qq.x;
            acc = fmaf(qq.y, fexp2(d * d * (-L2E)), acc);
        }
        acc *= mp;
        acc = wave_sum_shfl(acc);
        if ((tid & 63) == 0) atomicAdd(out, acc);
    }
}

// ll + le terms. Grid (32, 16): 32 p-chunks of 256 x 16 q-splits of 512.
__global__ __launch_bounds__(256) void ll_le(
    const float* __restrict__ texp,
    const float* __restrict__ tl,
    float* __restrict__ out)
{
    __shared__ __align__(16) float4 qbuf[512];
    __shared__ float red[4];

    const int pc = blockIdx.x;
    const int qs = blockIdx.y;
    const int tid = threadIdx.x;

    const int p = pc * 256 + tid;
    const float tlp = tl[p];
    const float mlp = (tlp < TMAXV && tlp > 0.0f) ? 1.0f : 0.0f;

    const int q0 = qs * 512;
    for (int i = tid; i < 512; i += 256) {
        float tq = tl[q0 + i];
        float mq = (tq < TMAXV && tq > 0.0f) ? 1.0f : 0.0f;
        float te = texp[q0 + i];
        float me = (te < TMAXV && te > 0.0f) ? 1.0f : 0.0f;
        qbuf[i] = make_float4(tq, mq, te, me);
    }
    __syncthreads();

    float val = 0.0f;
    // learner times are cumsum of Exp(1) increments: most p-points exceed T_MAX;
    // fully-masked waves skip the whole q-loop (wave-uniform branch).
    if (__ballot(mlp != 0.0f) != 0ULL) {
        float a_ll = 0.0f, a_le = 0.0f;
        #pragma unroll 4
        for (int i = 0; i < 512; ++i) {
            float4 q = qbuf[i];
            float d1 = tlp - q.x;
            a_ll = fmaf(q.y, fexp2(d1 * d1 * (-L2E)), a_ll);
            float d2 = tlp - q.z;
            a_le = fmaf(q.w, fexp2(d2 * d2 * (-L2E)), a_le);
        }
        val = mlp * (a_ll - 2.0f * a_le);
    }

    val = wave_sum_shfl(val);
    if ((tid & 63) == 0) red[tid >> 6] = val;
    __syncthreads();
    if (tid == 0) atomicAdd(out, red[0] + red[1] + red[2] + red[3]);
}

extern "C" void kernel_launch(void* const* d_in, const int* in_sizes, int n_in,
                              void* d_out, int out_size, void* d_ws, size_t ws_size,
                              hipStream_t stream) {
    const float* upool = (const float*)d_in[0];
    const float* texp  = (const float*)d_in[1];
    const float* Wih   = (const float*)d_in[2];
    const float* Whh   = (const float*)d_in[3];
    const float* bih   = (const float*)d_in[4];
    const float* bhh   = (const float*)d_in[5];
    const float* Vw    = (const float*)d_in[6];
    const float* Vb    = (const float*)d_in[7];
    float* out = (float*)d_out;
    float* tl  = (float*)d_ws;   // 8192 floats = 32 KB

    hipMemsetAsync(out, 0, sizeof(float), stream);
    hipLaunchKernelGGL(gen_and_ee, dim3(BATCH + 128), dim3(256), 0, stream,
                       upool, texp, Wih, Whh, bih, bhh, Vw, Vb, tl, out);
    hipLaunchKernelGGL(ll_le, dim3(32, 16), dim3(256), 0, stream, texp, tl, out);
}

// Round 8
// 156.012 us; speedup vs baseline: 1.0743x; 1.0128x over previous
//
#include <hip/hip_runtime.h>
#include <math.h>

#define HIDDEN 64
#define SEQ 128
#define BATCH 64
#define NPTS (BATCH * SEQ)   // 8192
#define TMAXV 20.0f
#define L2E 1.4426950408889634f
#define LN2 0.6931471805599453f

typedef float v2f __attribute__((ext_vector_type(2)));

__device__ __forceinline__ float fexp2(float x) { return __builtin_amdgcn_exp2f(x); }
__device__ __forceinline__ float flog2(float x) { return __builtin_amdgcn_logf(x); }
__device__ __forceinline__ float frcp(float x)  { return __builtin_amdgcn_rcpf(x); }
__device__ __forceinline__ float fsigmoid(float x) { return frcp(1.0f + fexp2(-x * L2E)); }
__device__ __forceinline__ float ftanh(float x)    { return 1.0f - 2.0f * frcp(1.0f + fexp2(2.0f * x * L2E)); }

// Raw barrier: orders LDS only (lgkmcnt), does NOT drain vmcnt.
__device__ __forceinline__ void barrier_lds_only() {
    asm volatile("s_waitcnt lgkmcnt(0)" ::: "memory");
    __builtin_amdgcn_s_barrier();
}

// Identity cross-lane pass (ds_bpermute with addr = lane*4). Bit-exact identity,
// but the result is a cross-lane intrinsic value the compiler cannot
// rematerialize -> it must stay VGPR-resident instead of re-loading each step.
__device__ __forceinline__ float keepf(float x, int lane4) {
    return __int_as_float(__builtin_amdgcn_ds_bpermute(lane4, __float_as_int(x)));
}

// ---- DPP wave64 sum: VALU-pipe cross-lane (no LDS round trips). Result uniform.
template <int CTRL>
__device__ __forceinline__ float dpp_mov(float x) {
    int r = __builtin_amdgcn_update_dpp(0, __float_as_int(x), CTRL, 0xf, 0xf, false);
    return __int_as_float(r);
}
__device__ __forceinline__ float wave_sum_dpp(float x) {
    x += dpp_mov<0x111>(x);   // row_shr:1
    x += dpp_mov<0x112>(x);   // row_shr:2
    x += dpp_mov<0x114>(x);   // row_shr:4
    x += dpp_mov<0x118>(x);   // row_shr:8  -> lane 16r+15 = row sum
    x += dpp_mov<0x142>(x);   // row_bcast:15
    x += dpp_mov<0x143>(x);   // row_bcast:31 -> lane 63 = total
    return __int_as_float(__builtin_amdgcn_readlane(__float_as_int(x), 63));
}

__device__ __forceinline__ float wave_sum_shfl(float v) {
    v += __shfl_xor(v, 1);  v += __shfl_xor(v, 2);  v += __shfl_xor(v, 4);
    v += __shfl_xor(v, 8);  v += __shfl_xor(v, 16); v += __shfl_xor(v, 32);
    return v;
}

// Blocks [0,64): LSTM rollout, one batch per block, 256 threads (thread j = gate-row j).
// KEY CHANGE vs r3 (68us): W_hh row values pass through identity ds_bpermute at
// init -> non-rematerializable -> must be kept in 64 VGPRs across the step loop
// (budget 512 via __launch_bounds__(256,1)). Removes the 64 KB/step/CU weight
// re-stream that r3/r5/r6 measured as the wall on every memory pipe.
// LDS canary: lu_s padded (+128 B) so the counter CSV proves this binary ran.
// Blocks [64,192): expert-expert MMD term (input-only) on the idle CUs.
__global__ __launch_bounds__(256, 1) void gen_and_ee(
    const float* __restrict__ upool,   // [B,S]
    const float* __restrict__ texp,    // [B,S]
    const float* __restrict__ Wih,     // [256]
    const float* __restrict__ Whh,     // [256,64]
    const float* __restrict__ bih,     // [256]
    const float* __restrict__ bhh,     // [256]
    const float* __restrict__ Vw,      // [64]
    const float* __restrict__ Vb,      // [1]
    float* __restrict__ tl,            // [NPTS] workspace
    float* __restrict__ out)           // [1] loss accumulator
{
    __shared__ float lu_s[SEQ + 32];               // +32 floats: build canary
    __shared__ float act_s[2][256];                 // double-buffered gate activations
    __shared__ __align__(16) float hx_s[4][64];     // per-wave private hx replicas
    __shared__ float2 qbuf[2048];

    const int bid = blockIdx.x;
    const int tid = threadIdx.x;

    if (bid < BATCH) {
        const int h  = tid & 63;
        const int wv = tid >> 6;
        const int lane4 =
            __builtin_amdgcn_mbcnt_hi(~0u, __builtin_amdgcn_mbcnt_lo(~0u, 0)) << 2;

        // W_hh row `tid` -> registers, laundered through identity bpermute.
        v2f w2[32];
        const float4* wrow = (const float4*)(Whh + tid * 64);
        #pragma unroll
        for (int k = 0; k < 16; ++k) {
            float4 v = wrow[k];
            w2[2 * k]     = (v2f){keepf(v.x, lane4), keepf(v.y, lane4)};
            w2[2 * k + 1] = (v2f){keepf(v.z, lane4), keepf(v.w, lane4)};
        }
        const float bias = bih[tid] + bhh[tid];
        const float wih  = Wih[tid];
        const float vw   = Vw[h];      // all waves: redundant sigma reduction
        const float vb   = Vb[0];

        if (tid < SEQ) lu_s[tid] = -flog2(upool[bid * SEQ + tid]) * LN2;
        hx_s[wv][h] = 0.0f;            // every wave zeroes its own replica
        float cx = 0.0f;
        barrier_lds_only();

        // step 0: hx = 0 -> sigma = elu(Vb)+1 (uniform)
        float sg0 = (vb > 0.0f) ? (vb + 1.0f) : fexp2(vb * L2E);
        float cum = lu_s[0] * frcp(sg0);
        float keep = (tid == 0) ? cum : 0.0f;   // thread t keeps cum of step t

        #pragma unroll 1
        for (int s = 0; s < SEQ - 1; ++s) {
            // gate-row dot hx, from this wave's private replica (broadcast b128 reads)
            const float4* h4 = (const float4*)hx_s[wv];
            v2f a0 = {0.f, 0.f}, a1 = {0.f, 0.f}, a2 = {0.f, 0.f}, a3 = {0.f, 0.f};
            #pragma unroll
            for (int k = 0; k < 16; k += 2) {
                float4 va = h4[k];
                float4 vbq = h4[k + 1];
                a0 = a0 + w2[2 * k]     * (v2f){va.x, va.y};
                a1 = a1 + w2[2 * k + 1] * (v2f){va.z, va.w};
                a2 = a2 + w2[2 * k + 2] * (v2f){vbq.x, vbq.y};
                a3 = a3 + w2[2 * k + 3] * (v2f){vbq.z, vbq.w};
            }
            v2f aa = (a0 + a1) + (a2 + a3);
            float g = (aa.x + aa.y) + bias + cum * wih;
            float a = (wv == 2) ? ftanh(g) : fsigmoid(g);
            act_s[s & 1][tid] = a;
            barrier_lds_only();        // the ONLY barrier per step; no vmcnt drain

            // redundant cell update in every wave (bit-identical across waves)
            float ig = act_s[s & 1][h];
            float fg = act_s[s & 1][64 + h];
            float gg = act_s[s & 1][128 + h];
            float og = act_s[s & 1][192 + h];
            cx = fg * cx + ig * gg;
            float hx = og * ftanh(cx);
            hx_s[wv][h] = hx;          // own replica; in-wave lgkmcnt ordering only

            float tot = wave_sum_dpp(hx * vw);
            float xx  = tot + vb;
            float sg  = (xx > 0.0f) ? (xx + 1.0f) : fexp2(xx * L2E);
            cum += lu_s[s + 1] * frcp(sg);

            keep = (tid == s + 1) ? cum : keep;   // threads 128..255 never match
        }
        if (tid < SEQ) tl[bid * SEQ + tid] = keep;
    } else {
        // ---------------- expert-expert MMD term ----------------
        const int eb = bid - BATCH;      // 0..127
        const int pc = eb & 31;          // p-chunk (256 points)
        const int qs = eb >> 5;          // q-split (2048 points)

        const int p = pc * 256 + tid;
        const float tp = texp[p];
        const float mp = (tp < TMAXV && tp > 0.0f) ? 1.0f : 0.0f;

        const int q0 = qs * 2048;
        for (int i = tid; i < 2048; i += 256) {
            float tq = texp[q0 + i];
            float mq = (tq < TMAXV && tq > 0.0f) ? 1.0f : 0.0f;
            qbuf[i] = make_float2(tq, mq);
        }
        __syncthreads();

        float acc = 0.0f;
        #pragma unroll 4
        for (int i = 0; i < 2048; ++i) {
            float2 qq = qbuf[i];
            float d = tp - qq.x;
            acc = fmaf(qq.y, fexp2(d * d * (-L2E)), acc);
        }
        acc *= mp;
        acc = wave_sum_shfl(acc);
        if ((tid & 63) == 0) atomicAdd(out, acc);
    }
}

// ll + le terms. Grid (32, 16): 32 p-chunks of 256 x 16 q-splits of 512.
__global__ __launch_bounds__(256) void ll_le(
    const float* __restrict__ texp,
    const float* __restrict__ tl,
    float* __restrict__ out)
{
    __shared__ __align__(16) float4 qbuf[512];
    __shared__ float red[4];

    const int pc = blockIdx.x;
    const int qs = blockIdx.y;
    const int tid = threadIdx.x;

    const int p = pc * 256 + tid;
    const float tlp = tl[p];
    const float mlp = (tlp < TMAXV && tlp > 0.0f) ? 1.0f : 0.0f;

    const int q0 = qs * 512;
    for (int i = tid; i < 512; i += 256) {
        float tq = tl[q0 + i];
        float mq = (tq < TMAXV && tq > 0.0f) ? 1.0f : 0.0f;
        float te = texp[q0 + i];
        float me = (te < TMAXV && te > 0.0f) ? 1.0f : 0.0f;
        qbuf[i] = make_float4(tq, mq, te, me);
    }
    __syncthreads();

    float val = 0.0f;
    // learner times are cumsum of Exp(1) increments: most p-points exceed T_MAX;
    // fully-masked waves skip the whole q-loop (wave-uniform branch).
    if (__ballot(mlp != 0.0f) != 0ULL) {
        float a_ll = 0.0f, a_le = 0.0f;
        #pragma unroll 4
        for (int i = 0; i < 512; ++i) {
            float4 q = qbuf[i];
            float d1 = tlp - q.x;
            a_ll = fmaf(q.y, fexp2(d1 * d1 * (-L2E)), a_ll);
            float d2 = tlp - q.z;
            a_le = fmaf(q.w, fexp2(d2 * d2 * (-L2E)), a_le);
        }
        val = mlp * (a_ll - 2.0f * a_le);
    }

    val = wave_sum_shfl(val);
    if ((tid & 63) == 0) red[tid >> 6] = val;
    __syncthreads();
    if (tid == 0) atomicAdd(out, red[0] + red[1] + red[2] + red[3]);
}

extern "C" void kernel_launch(void* const* d_in, const int* in_sizes, int n_in,
                              void* d_out, int out_size, void* d_ws, size_t ws_size,
                              hipStream_t stream) {
    const float* upool = (const float*)d_in[0];
    const float* texp  = (const float*)d_in[1];
    const float* Wih   = (const float*)d_in[2];
    const float* Whh   = (const float*)d_in[3];
    const float* bih   = (const float*)d_in[4];
    const float* bhh   = (const float*)d_in[5];
    const float* Vw    = (const float*)d_in[6];
    const float* Vb    = (const float*)d_in[7];
    float* out = (float*)d_out;
    float* tl  = (float*)d_ws;   // 8192 floats = 32 KB

    hipMemsetAsync(out, 0, sizeof(float), stream);
    hipLaunchKernelGGL(gen_and_ee, dim3(BATCH + 128), dim3(256), 0, stream,
                       upool, texp, Wih, Whh, bih, bhh, Vw, Vb, tl, out);
    hipLaunchKernelGGL(ll_le, dim3(32, 16), dim3(256), 0, stream, texp, tl, out);
}